// Round 5
// baseline (200.161 us; speedup 1.0000x reference)
//
#include <hip/hip_runtime.h>

using bf8   = __attribute__((ext_vector_type(8))) short;
using f32x4 = __attribute__((ext_vector_type(4))) float;
typedef unsigned short u16x4 __attribute__((ext_vector_type(4)));  // 8B, align 8

__device__ inline unsigned short f2bf(float f) {
  unsigned u = __float_as_uint(f);
  return (unsigned short)((u + 0x7FFFu + ((u >> 16) & 1u)) >> 16);  // RNE
}
__device__ inline float bf2f(unsigned short h) {
  return __uint_as_float(((unsigned)h) << 16);
}

// Composite filters: 2nd-level db2 DWT on the hi branch of the 1st level
// collapses to one 10-tap stride-4 conv along channels.
struct Gs { float g0[10]; float g1[10]; };
__host__ __device__ constexpr Gs make_g() {
  double H0[4] = {0.48296291314469025, 0.836516303737469,
                  0.22414386804185735, -0.12940952255092145};
  double H1[4] = {0.12940952255092145, -0.22414386804185735,
                  0.836516303737469, -0.48296291314469025};
  Gs r{};
  for (int d = 0; d < 10; ++d) {
    double a = 0.0, b = 0.0;
    for (int k = 0; k < 4; ++k) {
      int j = d - 2 * k;
      if (j >= 0 && j < 4) { a += H0[k] * H1[j]; b += H1[k] * H1[j]; }
    }
    r.g0[d] = (float)a; r.g1[d] = (float)b;
  }
  return r;
}

// ---------------------------------------------------------------------------
// K1: x fp32 [16][360][4096] -> A bf16 (flat [16][180][4096]); float4/thread.
// Grid 559 = 512 DWT blocks (8 seg x 16 b x 4 s-chunks, 2 blocks/CU) + 47
// weight-prep blocks (w1 -> bf16 [128][104], w2 -> bf16 [256][136]).
__global__ __launch_bounds__(256) void dwt2_kernel(const float* __restrict__ x,
                                                   unsigned short* __restrict__ A,
                                                   const float* __restrict__ w1,
                                                   const float* __restrict__ w2,
                                                   unsigned short* __restrict__ w1b,
                                                   unsigned short* __restrict__ w2b) {
  constexpr Gs G = make_g();
  const int bx = blockIdx.x;
  if (bx >= 512) {  // ---- weight prep: 47 blocks x 1024 elems = 48128 ----
    const int e = bx - 512;
#pragma unroll
    for (int t = 0; t < 4; ++t) {
      const int i = e * 1024 + t * 256 + threadIdx.x;
      if (i < 13312) {                       // w1b: 128 x 104
        const int o = i / 104, k = i - 104 * o;
        w1b[i] = (k < 90) ? f2bf(w1[o * 90 + k]) : (unsigned short)0;
      } else {                               // w2b: 256 x 136
        const int j = i - 13312;
        const int o = j / 136, k = j - 136 * o;
        w2b[j] = (k < 128) ? f2bf(w2[o * 128 + k]) : (unsigned short)0;
      }
    }
    return;
  }

  const int seg   = bx & 7;
  const int pb    = bx >> 3;      // 0..63
  const int b     = pb >> 2;      // 0..15
  const int chunk = pb & 3;       // 0..3
  const int s     = chunk * 1024 + 4 * threadIdx.x;

  const float4* xb = (const float4*)(x + (size_t)b * 360 * 4096 + s);
  unsigned short* Ab = A + (size_t)b * 180 * 4096 + s;
  // channel stride: 1024 float4

  const int c0 = (seg * 90) >> 3;
  const int c1 = ((seg + 1) * 90) >> 3;

  float4 w[10];
  const int base = 4 * c0 - 6;
#pragma unroll
  for (int i = 0; i < 10; ++i) {
    const int idx = base + i;
    w[i] = (idx >= 0) ? xb[(size_t)idx * 1024] : float4{0.f, 0.f, 0.f, 0.f};
  }

  for (int c = c0; c < c1; ++c) {
    float4 nx[4];
    const bool pf = (c + 1 < c1);
    const int nb = 4 * c + 4;  // <= 359
#pragma unroll
    for (int i = 0; i < 4; ++i)
      nx[i] = pf ? xb[(size_t)(nb + i) * 1024] : float4{0.f, 0.f, 0.f, 0.f};

    float4 lo{0.f, 0.f, 0.f, 0.f}, hi{0.f, 0.f, 0.f, 0.f};
#pragma unroll
    for (int d = 0; d < 10; ++d) {
      lo.x = fmaf(G.g0[d], w[d].x, lo.x);
      lo.y = fmaf(G.g0[d], w[d].y, lo.y);
      lo.z = fmaf(G.g0[d], w[d].z, lo.z);
      lo.w = fmaf(G.g0[d], w[d].w, lo.w);
      hi.x = fmaf(G.g1[d], w[d].x, hi.x);
      hi.y = fmaf(G.g1[d], w[d].y, hi.y);
      hi.z = fmaf(G.g1[d], w[d].z, hi.z);
      hi.w = fmaf(G.g1[d], w[d].w, hi.w);
    }
    *(ushort4*)&Ab[(size_t)c * 4096] =
        ushort4{f2bf(lo.x), f2bf(lo.y), f2bf(lo.z), f2bf(lo.w)};
    *(ushort4*)&Ab[(size_t)(c + 90) * 4096] =
        ushort4{f2bf(hi.x), f2bf(hi.y), f2bf(hi.z), f2bf(hi.w)};
#pragma unroll
    for (int i = 0; i < 6; ++i) w[i] = w[i + 4];
#pragma unroll
    for (int i = 0; i < 4; ++i) w[6 + i] = nx[i];
  }
}

// ---------------------------------------------------------------------------
// K2: conv(in-register, direct-from-global A) + fc1 (96->128, relu) +
// fc2 FULL (128->256), bf16 MFMA 16x16x32. Grid 1024 blocks x 128 thr
// (2 waves), 64 rows/block. Each wave owns 32 rows as TWO 16-row m-tiles
// (weight B-fragment reuse, the r4 win). 128-thr blocks + 17.4KB LDS +
// __launch_bounds__(128,4) target 8 blocks/CU = 16 waves/CU — double r4's
// TLP, to hide the serial conv->fc1->fc2 load-latency chain (the r4 residual:
// ~29us vs 14us traffic floor at only 2 waves/SIMD).
// ZERO barriers:
//  - conv windows: u16x4 (8B) global loads; A rows 8B-aligned (360B stride).
//  - MFMA B-fragments (w1b/w2b rows, 16B-aligned) read directly from global;
//    w1b (26.6KB) L1-resident, w2b (69.6KB) streams from L2.
//  - H handoff is wave-private (ep1 writes rows 32w+16m+4q+r; fc2 reads rows
//    32w+16m+l15) -> no cross-wave visibility needed.
// Weights sit BEFORE A in the workspace so the ks=0/q=0 window's 8-byte
// under-read of row 0 stays inside the allocation.
// GRID MUST BE 1024 (65536 rows / 64 rows-per-block).
// Frag layouts (validated): A/B row = lane&15, k = (lane>>4)*8 + j;
// C/D col(B-row) = lane&15, row(A-row) = (lane>>4)*4+reg.
__global__ __launch_bounds__(128, 4) void mlp_direct_kernel(
    const unsigned short* __restrict__ A,
    const float* __restrict__ cw, const float* __restrict__ cbp,
    const unsigned short* __restrict__ w1b,
    const unsigned short* __restrict__ w2b,
    const float* __restrict__ b1, const float* __restrict__ b2,
    float* __restrict__ out) {
  __shared__ unsigned short Hs[64 * 136];  // 17,408 B; stride 136 keeps b128 reads 16B-aligned

  const int tid  = threadIdx.x;
  const int w    = tid >> 6, lane = tid & 63;  // w in {0,1}
  const int l15  = lane & 15, q = lane >> 4;
  const size_t g0 = (size_t)blockIdx.x * 64;

  float cwr[14];  // uniform -> scalar regs
#pragma unroll
  for (int k = 0; k < 14; ++k) cwr[k] = cw[k];
  const float cbv = cbp[0];

  float b1v[8], b2v[16];  // per-lane bias (o = 16*nt + l15)
#pragma unroll
  for (int nt = 0; nt < 8; ++nt) b1v[nt] = b1[16 * nt + l15];
#pragma unroll
  for (int nt = 0; nt < 16; ++nt) b2v[nt] = b2[16 * nt + l15];

  // ---- conv -> fc1 A-fragments (2 m-tiles), straight from global ----
  // m-tile m, k-step ks: fragment = conv outputs j = 32*ks+8*q .. +8 of row
  // 32w+16m+l15. Inputs: A[row][j0-3..j0+10] (v0), A[row][90+j0-3..] (v1).
  // 8B-aligned u16x4 chunks: v0 = idx j0-4+4k (k<4), v1 = idx j0+84+4k (k<5).
  bf8 ya[2][3];
#pragma unroll
  for (int m = 0; m < 2; ++m) {
    const unsigned short* Ar = A + (size_t)(g0 + 32 * w + 16 * m + l15) * 180;
#pragma unroll
    for (int ks = 0; ks < 3; ++ks) {
      const int j0 = 32 * ks + 8 * q;
      u16x4 L[4], Hc[5];
#pragma unroll
      for (int k = 0; k < 4; ++k) L[k] = *(const u16x4*)(Ar + j0 - 4 + 4 * k);
#pragma unroll
      for (int k = 0; k < 5; ++k) Hc[k] = *(const u16x4*)(Ar + j0 + 84 + 4 * k);

      float v0[14], v1[14];
#pragma unroll
      for (int t = 0; t < 14; ++t) {
        const int mm = j0 - 3 + t;
        const bool ok = (mm >= 0) && (mm < 90);
        v0[t] = ok ? bf2f((unsigned short)L[(t + 1) >> 2][(t + 1) & 3]) : 0.0f;
        v1[t] = ok ? bf2f((unsigned short)Hc[(t + 3) >> 2][(t + 3) & 3]) : 0.0f;
      }
      bf8 r8;
#pragma unroll
      for (int d = 0; d < 8; ++d) {
        const int j = j0 + d;
        unsigned short rv = 0;
        if (j < 90) {  // cols 90..95 stay zero (fc1 K-slots 90..95 are zero)
          float acc = cbv;
#pragma unroll
          for (int k = 0; k < 7; ++k) {  // same FMA order as validated conv
            acc = fmaf(v0[d + k], cwr[k], acc);
            acc = fmaf(v1[d + k], cwr[7 + k], acc);
          }
          rv = f2bf(fmaxf(acc, 0.0f));
        }
        r8[d] = (short)rv;
      }
      ya[m][ks] = r8;
    }
  }

  // ---- fc1: K=96; each wb fragment (global w1b) feeds both m-tiles ----
#pragma unroll
  for (int nt = 0; nt < 8; ++nt) {
    bf8 wb[3];
#pragma unroll
    for (int ks = 0; ks < 3; ++ks)
      wb[ks] = *(const bf8*)&w1b[(16 * nt + l15) * 104 + 32 * ks + 8 * q];
    f32x4 a0 = {0.f, 0.f, 0.f, 0.f}, a1 = {0.f, 0.f, 0.f, 0.f};
#pragma unroll
    for (int ks = 0; ks < 3; ++ks) {
      a0 = __builtin_amdgcn_mfma_f32_16x16x32_bf16(ya[0][ks], wb[ks], a0, 0, 0, 0);
      a1 = __builtin_amdgcn_mfma_f32_16x16x32_bf16(ya[1][ks], wb[ks], a1, 0, 0, 0);
    }
    // epilogue 1: +b1, relu -> H[n][o1] bf16 (wave-private rows)
#pragma unroll
    for (int r = 0; r < 4; ++r) {
      const int o = 16 * nt + l15;
      Hs[(32 * w + 4 * q + r) * 136 + o]      = f2bf(fmaxf(a0[r] + b1v[nt], 0.0f));
      Hs[(32 * w + 16 + 4 * q + r) * 136 + o] = f2bf(fmaxf(a1[r] + b1v[nt], 0.0f));
    }
  }

  // ---- fc2: K=128, 16 output tiles; wb (global w2b) feeds both m-tiles ----
  bf8 ha[2][4];
#pragma unroll
  for (int m = 0; m < 2; ++m)
#pragma unroll
    for (int ks = 0; ks < 4; ++ks)
      ha[m][ks] = *(const bf8*)&Hs[(32 * w + 16 * m + l15) * 136 + 32 * ks + 8 * q];

#pragma unroll 4
  for (int nt = 0; nt < 16; ++nt) {
    bf8 wb[4];
#pragma unroll
    for (int ks = 0; ks < 4; ++ks)
      wb[ks] = *(const bf8*)&w2b[(16 * nt + l15) * 136 + 32 * ks + 8 * q];
    f32x4 a0 = {0.f, 0.f, 0.f, 0.f}, a1 = {0.f, 0.f, 0.f, 0.f};
#pragma unroll
    for (int ks = 0; ks < 4; ++ks) {
      a0 = __builtin_amdgcn_mfma_f32_16x16x32_bf16(ha[0][ks], wb[ks], a0, 0, 0, 0);
      a1 = __builtin_amdgcn_mfma_f32_16x16x32_bf16(ha[1][ks], wb[ks], a1, 0, 0, 0);
    }
#pragma unroll
    for (int r = 0; r < 4; ++r) {
      const int o = 16 * nt + l15;
      out[(g0 + 32 * w + 4 * q + r) * 256 + o]      = a0[r] + b2v[nt];
      out[(g0 + 32 * w + 16 + 4 * q + r) * 256 + o] = a1[r] + b2v[nt];
    }
  }
}

// ---------------------------------------------------------------------------
extern "C" void kernel_launch(void* const* d_in, const int* in_sizes, int n_in,
                              void* d_out, int out_size, void* d_ws, size_t ws_size,
                              hipStream_t stream) {
  const float* x  = (const float*)d_in[0];
  const float* cw = (const float*)d_in[1];
  const float* cb = (const float*)d_in[2];
  const float* w1 = (const float*)d_in[3];
  const float* b1 = (const float*)d_in[4];
  const float* w2 = (const float*)d_in[5];
  const float* b2 = (const float*)d_in[6];
  float* outp = (float*)d_out;

  // Weights FIRST so A's row-0 conv window under-read stays in-allocation.
  unsigned short* w1b = (unsigned short*)d_ws;      // 13312 u16 (128x104)
  unsigned short* w2b = w1b + 13312;                // 34816 u16 (256x136)
  unsigned short* Abf = w1b + 48128;                // 16*180*4096 u16 = 23.6 MB

  dwt2_kernel<<<559, 256, 0, stream>>>(x, Abf, w1, w2, w1b, w2b);
  mlp_direct_kernel<<<1024, 128, 0, stream>>>(Abf, cw, cb, w1b, w2b, b1, b2, outp);
}

// Round 7
// 193.552 us; speedup vs baseline: 1.0341x; 1.0341x over previous
//
#include <hip/hip_runtime.h>

using bf8   = __attribute__((ext_vector_type(8))) short;
using f32x4 = __attribute__((ext_vector_type(4))) float;
typedef unsigned short u16x4 __attribute__((ext_vector_type(4)));  // 8B, align 8

__device__ inline unsigned short f2bf(float f) {
  unsigned u = __float_as_uint(f);
  return (unsigned short)((u + 0x7FFFu + ((u >> 16) & 1u)) >> 16);  // RNE
}
__device__ inline float bf2f(unsigned short h) {
  return __uint_as_float(((unsigned)h) << 16);
}

// Composite filters: 2nd-level db2 DWT on the hi branch of the 1st level
// collapses to one 10-tap stride-4 conv along channels.
struct Gs { float g0[10]; float g1[10]; };
__host__ __device__ constexpr Gs make_g() {
  double H0[4] = {0.48296291314469025, 0.836516303737469,
                  0.22414386804185735, -0.12940952255092145};
  double H1[4] = {0.12940952255092145, -0.22414386804185735,
                  0.836516303737469, -0.48296291314469025};
  Gs r{};
  for (int d = 0; d < 10; ++d) {
    double a = 0.0, b = 0.0;
    for (int k = 0; k < 4; ++k) {
      int j = d - 2 * k;
      if (j >= 0 && j < 4) { a += H0[k] * H1[j]; b += H1[k] * H1[j]; }
    }
    r.g0[d] = (float)a; r.g1[d] = (float)b;
  }
  return r;
}

// ---------------------------------------------------------------------------
// K1: x fp32 [16][360][4096] -> A bf16 (flat [16][180][4096]); float4/thread.
// Grid 559 = 512 DWT blocks (8 seg x 16 b x 4 s-chunks, 2 blocks/CU) + 47
// weight-prep blocks (w1 -> bf16 [128][104], w2 -> bf16 [256][136]).
__global__ __launch_bounds__(256) void dwt2_kernel(const float* __restrict__ x,
                                                   unsigned short* __restrict__ A,
                                                   const float* __restrict__ w1,
                                                   const float* __restrict__ w2,
                                                   unsigned short* __restrict__ w1b,
                                                   unsigned short* __restrict__ w2b) {
  constexpr Gs G = make_g();
  const int bx = blockIdx.x;
  if (bx >= 512) {  // ---- weight prep: 47 blocks x 1024 elems = 48128 ----
    const int e = bx - 512;
#pragma unroll
    for (int t = 0; t < 4; ++t) {
      const int i = e * 1024 + t * 256 + threadIdx.x;
      if (i < 13312) {                       // w1b: 128 x 104
        const int o = i / 104, k = i - 104 * o;
        w1b[i] = (k < 90) ? f2bf(w1[o * 90 + k]) : (unsigned short)0;
      } else {                               // w2b: 256 x 136
        const int j = i - 13312;
        const int o = j / 136, k = j - 136 * o;
        w2b[j] = (k < 128) ? f2bf(w2[o * 128 + k]) : (unsigned short)0;
      }
    }
    return;
  }

  const int seg   = bx & 7;
  const int pb    = bx >> 3;      // 0..63
  const int b     = pb >> 2;      // 0..15
  const int chunk = pb & 3;       // 0..3
  const int s     = chunk * 1024 + 4 * threadIdx.x;

  const float4* xb = (const float4*)(x + (size_t)b * 360 * 4096 + s);
  unsigned short* Ab = A + (size_t)b * 180 * 4096 + s;
  // channel stride: 1024 float4

  const int c0 = (seg * 90) >> 3;
  const int c1 = ((seg + 1) * 90) >> 3;

  float4 w[10];
  const int base = 4 * c0 - 6;
#pragma unroll
  for (int i = 0; i < 10; ++i) {
    const int idx = base + i;
    w[i] = (idx >= 0) ? xb[(size_t)idx * 1024] : float4{0.f, 0.f, 0.f, 0.f};
  }

  for (int c = c0; c < c1; ++c) {
    float4 nx[4];
    const bool pf = (c + 1 < c1);
    const int nb = 4 * c + 4;  // <= 359
#pragma unroll
    for (int i = 0; i < 4; ++i)
      nx[i] = pf ? xb[(size_t)(nb + i) * 1024] : float4{0.f, 0.f, 0.f, 0.f};

    float4 lo{0.f, 0.f, 0.f, 0.f}, hi{0.f, 0.f, 0.f, 0.f};
#pragma unroll
    for (int d = 0; d < 10; ++d) {
      lo.x = fmaf(G.g0[d], w[d].x, lo.x);
      lo.y = fmaf(G.g0[d], w[d].y, lo.y);
      lo.z = fmaf(G.g0[d], w[d].z, lo.z);
      lo.w = fmaf(G.g0[d], w[d].w, lo.w);
      hi.x = fmaf(G.g1[d], w[d].x, hi.x);
      hi.y = fmaf(G.g1[d], w[d].y, hi.y);
      hi.z = fmaf(G.g1[d], w[d].z, hi.z);
      hi.w = fmaf(G.g1[d], w[d].w, hi.w);
    }
    *(ushort4*)&Ab[(size_t)c * 4096] =
        ushort4{f2bf(lo.x), f2bf(lo.y), f2bf(lo.z), f2bf(lo.w)};
    *(ushort4*)&Ab[(size_t)(c + 90) * 4096] =
        ushort4{f2bf(hi.x), f2bf(hi.y), f2bf(hi.z), f2bf(hi.w)};
#pragma unroll
    for (int i = 0; i < 6; ++i) w[i] = w[i + 4];
#pragma unroll
    for (int i = 0; i < 4; ++i) w[6 + i] = nx[i];
  }
}

// ---------------------------------------------------------------------------
// K2: conv(in-register, direct-from-global A) + fc1 (96->128, relu) +
// fc2 FULL (128->256), bf16 MFMA 16x16x32. Grid 256 blocks x 512 thr
// (8 waves), 256 rows/block, 1 block/CU (LDS 139.3KB), 8 waves/CU — same
// occupancy as r4 (r5 proved more TLP does NOT help; r2->r4 proved weight
// traffic DOES). This round: stage w2b in LDS once per block -> fc2
// B-fragments come from LDS, cutting w2b L1/L2 traffic 137MB -> 17.8MB and
// un-thrashing L1 (w1b 26.6KB becomes cleanly L1-resident for its global
// fragment reads).
// ONE barrier (after ep1): orders kernel-top w2B staging vs fc2 LDS reads;
// staging latency hides under the long conv+fc1 phase. Hs stays wave-private
// (ep1 writes rows 32w+16m+4q+r; fc2 reads rows 32w+16m+l15) -> no barrier
// needed for Hs itself.
// Conv windows: u16x4 (8B) global loads; A rows 8B-aligned (360B stride).
// Weights sit BEFORE A in the workspace so the ks=0/q=0 window's 8-byte
// under-read of row 0 stays inside the allocation.
// GRID MUST BE 256 (65536 rows / 256 rows-per-block).
// Frag layouts (validated): A/B row = lane&15, k = (lane>>4)*8 + j;
// C/D col(B-row) = lane&15, row(A-row) = (lane>>4)*4+reg.
__global__ __launch_bounds__(512, 1) void mlp_direct_kernel(
    const unsigned short* __restrict__ A,
    const float* __restrict__ cw, const float* __restrict__ cbp,
    const unsigned short* __restrict__ w1b,
    const unsigned short* __restrict__ w2b,
    const float* __restrict__ b1, const float* __restrict__ b2,
    float* __restrict__ out) {
  __shared__ unsigned short w2B[256 * 136];  // 69,632 B
  __shared__ unsigned short Hs[256 * 136];   // 69,632 B; stride 136 keeps b128 16B-aligned

  const int tid  = threadIdx.x;
  const int w    = tid >> 6, lane = tid & 63;  // w in 0..7
  const int l15  = lane & 15, q = lane >> 4;
  const size_t g0 = (size_t)blockIdx.x * 256;

  // ---- stage w2b -> LDS once (4352 uint4); consumed only after the barrier,
  // so the load latency hides under conv+fc1 ----
  {
    const uint4* s2 = (const uint4*)w2b;
    for (int i = tid; i < 4352; i += 512) ((uint4*)w2B)[i] = s2[i];
  }

  float cwr[14];  // uniform -> scalar regs
#pragma unroll
  for (int k = 0; k < 14; ++k) cwr[k] = cw[k];
  const float cbv = cbp[0];

  float b1v[8], b2v[16];  // per-lane bias (o = 16*nt + l15)
#pragma unroll
  for (int nt = 0; nt < 8; ++nt) b1v[nt] = b1[16 * nt + l15];
#pragma unroll
  for (int nt = 0; nt < 16; ++nt) b2v[nt] = b2[16 * nt + l15];

  // ---- conv -> fc1 A-fragments (2 m-tiles), straight from global ----
  // m-tile m, k-step ks: fragment = conv outputs j = 32*ks+8*q .. +8 of row
  // 32w+16m+l15. Inputs: A[row][j0-3..j0+10] (v0), A[row][90+j0-3..] (v1).
  // 8B-aligned u16x4 chunks: v0 = idx j0-4+4k (k<4), v1 = idx j0+84+4k (k<5).
  bf8 ya[2][3];
#pragma unroll
  for (int m = 0; m < 2; ++m) {
    const unsigned short* Ar = A + (size_t)(g0 + 32 * w + 16 * m + l15) * 180;
#pragma unroll
    for (int ks = 0; ks < 3; ++ks) {
      const int j0 = 32 * ks + 8 * q;
      u16x4 L[4], Hc[5];
#pragma unroll
      for (int k = 0; k < 4; ++k) L[k] = *(const u16x4*)(Ar + j0 - 4 + 4 * k);
#pragma unroll
      for (int k = 0; k < 5; ++k) Hc[k] = *(const u16x4*)(Ar + j0 + 84 + 4 * k);

      float v0[14], v1[14];
#pragma unroll
      for (int t = 0; t < 14; ++t) {
        const int mm = j0 - 3 + t;
        const bool ok = (mm >= 0) && (mm < 90);
        v0[t] = ok ? bf2f((unsigned short)L[(t + 1) >> 2][(t + 1) & 3]) : 0.0f;
        v1[t] = ok ? bf2f((unsigned short)Hc[(t + 3) >> 2][(t + 3) & 3]) : 0.0f;
      }
      bf8 r8;
#pragma unroll
      for (int d = 0; d < 8; ++d) {
        const int j = j0 + d;
        unsigned short rv = 0;
        if (j < 90) {  // cols 90..95 stay zero (fc1 K-slots 90..95 are zero)
          float acc = cbv;
#pragma unroll
          for (int k = 0; k < 7; ++k) {  // same FMA order as validated conv
            acc = fmaf(v0[d + k], cwr[k], acc);
            acc = fmaf(v1[d + k], cwr[7 + k], acc);
          }
          rv = f2bf(fmaxf(acc, 0.0f));
        }
        r8[d] = (short)rv;
      }
      ya[m][ks] = r8;
    }
  }

  // ---- fc1: K=96; wb fragments from global w1b (26.6KB, L1-resident);
  // each fragment feeds both m-tiles ----
#pragma unroll
  for (int nt = 0; nt < 8; ++nt) {
    bf8 wb[3];
#pragma unroll
    for (int ks = 0; ks < 3; ++ks)
      wb[ks] = *(const bf8*)&w1b[(16 * nt + l15) * 104 + 32 * ks + 8 * q];
    f32x4 a0 = {0.f, 0.f, 0.f, 0.f}, a1 = {0.f, 0.f, 0.f, 0.f};
#pragma unroll
    for (int ks = 0; ks < 3; ++ks) {
      a0 = __builtin_amdgcn_mfma_f32_16x16x32_bf16(ya[0][ks], wb[ks], a0, 0, 0, 0);
      a1 = __builtin_amdgcn_mfma_f32_16x16x32_bf16(ya[1][ks], wb[ks], a1, 0, 0, 0);
    }
    // epilogue 1: +b1, relu -> H[n][o1] bf16 (wave-private rows)
#pragma unroll
    for (int r = 0; r < 4; ++r) {
      const int o = 16 * nt + l15;
      Hs[(32 * w + 4 * q + r) * 136 + o]      = f2bf(fmaxf(a0[r] + b1v[nt], 0.0f));
      Hs[(32 * w + 16 + 4 * q + r) * 136 + o] = f2bf(fmaxf(a1[r] + b1v[nt], 0.0f));
    }
  }

  __syncthreads();  // w2B staging (kernel top) visible before fc2 LDS reads

  // ---- fc2: K=128, 16 output tiles; wb from LDS w2B feeds both m-tiles ----
  bf8 ha[2][4];
#pragma unroll
  for (int m = 0; m < 2; ++m)
#pragma unroll
    for (int ks = 0; ks < 4; ++ks)
      ha[m][ks] = *(const bf8*)&Hs[(32 * w + 16 * m + l15) * 136 + 32 * ks + 8 * q];

#pragma unroll 4
  for (int nt = 0; nt < 16; ++nt) {
    bf8 wb[4];
#pragma unroll
    for (int ks = 0; ks < 4; ++ks)
      wb[ks] = *(const bf8*)&w2B[(16 * nt + l15) * 136 + 32 * ks + 8 * q];
    f32x4 a0 = {0.f, 0.f, 0.f, 0.f}, a1 = {0.f, 0.f, 0.f, 0.f};
#pragma unroll
    for (int ks = 0; ks < 4; ++ks) {
      a0 = __builtin_amdgcn_mfma_f32_16x16x32_bf16(ha[0][ks], wb[ks], a0, 0, 0, 0);
      a1 = __builtin_amdgcn_mfma_f32_16x16x32_bf16(ha[1][ks], wb[ks], a1, 0, 0, 0);
    }
#pragma unroll
    for (int r = 0; r < 4; ++r) {
      const int o = 16 * nt + l15;
      out[(g0 + 32 * w + 4 * q + r) * 256 + o]      = a0[r] + b2v[nt];
      out[(g0 + 32 * w + 16 + 4 * q + r) * 256 + o] = a1[r] + b2v[nt];
    }
  }
}

// ---------------------------------------------------------------------------
extern "C" void kernel_launch(void* const* d_in, const int* in_sizes, int n_in,
                              void* d_out, int out_size, void* d_ws, size_t ws_size,
                              hipStream_t stream) {
  const float* x  = (const float*)d_in[0];
  const float* cw = (const float*)d_in[1];
  const float* cb = (const float*)d_in[2];
  const float* w1 = (const float*)d_in[3];
  const float* b1 = (const float*)d_in[4];
  const float* w2 = (const float*)d_in[5];
  const float* b2 = (const float*)d_in[6];
  float* outp = (float*)d_out;

  // Weights FIRST so A's row-0 conv window under-read stays in-allocation.
  unsigned short* w1b = (unsigned short*)d_ws;      // 13312 u16 (128x104)
  unsigned short* w2b = w1b + 13312;                // 34816 u16 (256x136)
  unsigned short* Abf = w1b + 48128;                // 16*180*4096 u16 = 23.6 MB

  dwt2_kernel<<<559, 256, 0, stream>>>(x, Abf, w1, w2, w1b, w2b);
  mlp_direct_kernel<<<256, 512, 0, stream>>>(Abf, cw, cb, w1b, w2b, b1, b2, outp);
}

// Round 8
// 189.447 us; speedup vs baseline: 1.0566x; 1.0217x over previous
//
#include <hip/hip_runtime.h>

using bf8   = __attribute__((ext_vector_type(8))) short;
using f32x4 = __attribute__((ext_vector_type(4))) float;
typedef unsigned short u16x4 __attribute__((ext_vector_type(4)));  // 8B, align 8

__device__ inline unsigned short f2bf(float f) {
  unsigned u = __float_as_uint(f);
  return (unsigned short)((u + 0x7FFFu + ((u >> 16) & 1u)) >> 16);  // RNE
}
__device__ inline float bf2f(unsigned short h) {
  return __uint_as_float(((unsigned)h) << 16);
}

// Composite filters: 2nd-level db2 DWT on the hi branch of the 1st level
// collapses to one 10-tap stride-4 conv along channels.
struct Gs { float g0[10]; float g1[10]; };
__host__ __device__ constexpr Gs make_g() {
  double H0[4] = {0.48296291314469025, 0.836516303737469,
                  0.22414386804185735, -0.12940952255092145};
  double H1[4] = {0.12940952255092145, -0.22414386804185735,
                  0.836516303737469, -0.48296291314469025};
  Gs r{};
  for (int d = 0; d < 10; ++d) {
    double a = 0.0, b = 0.0;
    for (int k = 0; k < 4; ++k) {
      int j = d - 2 * k;
      if (j >= 0 && j < 4) { a += H0[k] * H1[j]; b += H1[k] * H1[j]; }
    }
    r.g0[d] = (float)a; r.g1[d] = (float)b;
  }
  return r;
}

// ---------------------------------------------------------------------------
// K1: x fp32 [16][360][4096] -> A bf16 (flat [16][180][4096]); float4/thread.
// Grid 559 = 512 DWT blocks (8 seg x 16 b x 4 s-chunks, 2 blocks/CU) + 47
// weight-prep blocks (w1 -> bf16 [128][104], w2 -> bf16 [256][136]).
__global__ __launch_bounds__(256) void dwt2_kernel(const float* __restrict__ x,
                                                   unsigned short* __restrict__ A,
                                                   const float* __restrict__ w1,
                                                   const float* __restrict__ w2,
                                                   unsigned short* __restrict__ w1b,
                                                   unsigned short* __restrict__ w2b) {
  constexpr Gs G = make_g();
  const int bx = blockIdx.x;
  if (bx >= 512) {  // ---- weight prep: 47 blocks x 1024 elems = 48128 ----
    const int e = bx - 512;
#pragma unroll
    for (int t = 0; t < 4; ++t) {
      const int i = e * 1024 + t * 256 + threadIdx.x;
      if (i < 13312) {                       // w1b: 128 x 104
        const int o = i / 104, k = i - 104 * o;
        w1b[i] = (k < 90) ? f2bf(w1[o * 90 + k]) : (unsigned short)0;
      } else {                               // w2b: 256 x 136
        const int j = i - 13312;
        const int o = j / 136, k = j - 136 * o;
        w2b[j] = (k < 128) ? f2bf(w2[o * 128 + k]) : (unsigned short)0;
      }
    }
    return;
  }

  const int seg   = bx & 7;
  const int pb    = bx >> 3;      // 0..63
  const int b     = pb >> 2;      // 0..15
  const int chunk = pb & 3;       // 0..3
  const int s     = chunk * 1024 + 4 * threadIdx.x;

  const float4* xb = (const float4*)(x + (size_t)b * 360 * 4096 + s);
  unsigned short* Ab = A + (size_t)b * 180 * 4096 + s;
  // channel stride: 1024 float4

  const int c0 = (seg * 90) >> 3;
  const int c1 = ((seg + 1) * 90) >> 3;

  float4 w[10];
  const int base = 4 * c0 - 6;
#pragma unroll
  for (int i = 0; i < 10; ++i) {
    const int idx = base + i;
    w[i] = (idx >= 0) ? xb[(size_t)idx * 1024] : float4{0.f, 0.f, 0.f, 0.f};
  }

  for (int c = c0; c < c1; ++c) {
    float4 nx[4];
    const bool pf = (c + 1 < c1);
    const int nb = 4 * c + 4;  // <= 359
#pragma unroll
    for (int i = 0; i < 4; ++i)
      nx[i] = pf ? xb[(size_t)(nb + i) * 1024] : float4{0.f, 0.f, 0.f, 0.f};

    float4 lo{0.f, 0.f, 0.f, 0.f}, hi{0.f, 0.f, 0.f, 0.f};
#pragma unroll
    for (int d = 0; d < 10; ++d) {
      lo.x = fmaf(G.g0[d], w[d].x, lo.x);
      lo.y = fmaf(G.g0[d], w[d].y, lo.y);
      lo.z = fmaf(G.g0[d], w[d].z, lo.z);
      lo.w = fmaf(G.g0[d], w[d].w, lo.w);
      hi.x = fmaf(G.g1[d], w[d].x, hi.x);
      hi.y = fmaf(G.g1[d], w[d].y, hi.y);
      hi.z = fmaf(G.g1[d], w[d].z, hi.z);
      hi.w = fmaf(G.g1[d], w[d].w, hi.w);
    }
    *(ushort4*)&Ab[(size_t)c * 4096] =
        ushort4{f2bf(lo.x), f2bf(lo.y), f2bf(lo.z), f2bf(lo.w)};
    *(ushort4*)&Ab[(size_t)(c + 90) * 4096] =
        ushort4{f2bf(hi.x), f2bf(hi.y), f2bf(hi.z), f2bf(hi.w)};
#pragma unroll
    for (int i = 0; i < 6; ++i) w[i] = w[i + 4];
#pragma unroll
    for (int i = 0; i < 4; ++i) w[6 + i] = nx[i];
  }
}

// ---------------------------------------------------------------------------
// K2: conv(in-register, direct-from-global A) + fc1 (96->128, relu) +
// fc2 FULL (128->256), bf16 MFMA 16x16x32. Grid 512 blocks x 256 thr
// (4 waves), 128 rows/block, 2 blocks/CU. Each wave owns 32 rows as TWO
// 16-row m-tiles: every weight B-fragment load feeds 2 MFMAs (r4's proven
// win). This round: BOTH m-tiles' conv A-loads for a k-step are issued
// together (18 in-flight 8B loads/burst vs 9) before either tile's VALU —
// 2x MLP during the HBM-latency-exposed conv phase; per-output FMA order
// unchanged (bitwise-identical results).
// r5/r7 lessons kept: no extra TLP (null), no w2b LDS staging (null).
// ZERO barriers:
//  - conv windows: u16x4 (8B) global loads; A rows 8B-aligned (360B stride).
//  - MFMA B-fragments (w1b/w2b rows, 16B-aligned) read directly from global;
//    w1b (26.6KB) L1-resident, w2b (69.6KB) streams from L2.
//  - H handoff is wave-private (ep1 writes rows 32w+16m+4q+r; fc2 reads rows
//    32w+16m+l15) -> no cross-wave visibility needed.
// Weights sit BEFORE A in the workspace so the ks=0/q=0 window's 8-byte
// under-read of row 0 stays inside the allocation.
// GRID MUST BE 512 (65536 rows / 128 rows-per-block).
// Frag layouts (validated): A/B row = lane&15, k = (lane>>4)*8 + j;
// C/D col(B-row) = lane&15, row(A-row) = (lane>>4)*4+reg.
__global__ __launch_bounds__(256, 2) void mlp_direct_kernel(
    const unsigned short* __restrict__ A,
    const float* __restrict__ cw, const float* __restrict__ cbp,
    const unsigned short* __restrict__ w1b,
    const unsigned short* __restrict__ w2b,
    const float* __restrict__ b1, const float* __restrict__ b2,
    float* __restrict__ out) {
  __shared__ unsigned short Hs[128 * 136];  // 34,816 B; stride 136 keeps b128 reads 16B-aligned

  const int tid  = threadIdx.x;
  const int w    = tid >> 6, lane = tid & 63;
  const int l15  = lane & 15, q = lane >> 4;
  const size_t g0 = (size_t)blockIdx.x * 128;

  float cwr[14];  // uniform -> scalar regs
#pragma unroll
  for (int k = 0; k < 14; ++k) cwr[k] = cw[k];
  const float cbv = cbp[0];

  float b1v[8], b2v[16];  // per-lane bias (o = 16*nt + l15)
#pragma unroll
  for (int nt = 0; nt < 8; ++nt) b1v[nt] = b1[16 * nt + l15];
#pragma unroll
  for (int nt = 0; nt < 16; ++nt) b2v[nt] = b2[16 * nt + l15];

  // ---- conv -> fc1 A-fragments (2 m-tiles), straight from global ----
  // m-tile m, k-step ks: fragment = conv outputs j = 32*ks+8*q .. +8 of row
  // 32w+16m+l15. Inputs: A[row][j0-3..j0+10] (v0), A[row][90+j0-3..] (v1).
  // 8B-aligned u16x4 chunks: v0 = idx j0-4+4k (k<4), v1 = idx j0+84+4k (k<5).
  // Loads for BOTH m-tiles issue before either tile's VALU (MLP doubling).
  const unsigned short* Ar0 = A + (size_t)(g0 + 32 * w + l15) * 180;
  const unsigned short* Ar1 = Ar0 + 16 * 180;
  bf8 ya[2][3];
#pragma unroll
  for (int ks = 0; ks < 3; ++ks) {
    const int j0 = 32 * ks + 8 * q;
    u16x4 L[2][4], Hc[2][5];
#pragma unroll
    for (int k = 0; k < 4; ++k) {
      L[0][k] = *(const u16x4*)(Ar0 + j0 - 4 + 4 * k);
      L[1][k] = *(const u16x4*)(Ar1 + j0 - 4 + 4 * k);
    }
#pragma unroll
    for (int k = 0; k < 5; ++k) {
      Hc[0][k] = *(const u16x4*)(Ar0 + j0 + 84 + 4 * k);
      Hc[1][k] = *(const u16x4*)(Ar1 + j0 + 84 + 4 * k);
    }

#pragma unroll
    for (int m = 0; m < 2; ++m) {
      float v0[14], v1[14];
#pragma unroll
      for (int t = 0; t < 14; ++t) {
        const int mm = j0 - 3 + t;
        const bool ok = (mm >= 0) && (mm < 90);
        v0[t] = ok ? bf2f((unsigned short)L[m][(t + 1) >> 2][(t + 1) & 3]) : 0.0f;
        v1[t] = ok ? bf2f((unsigned short)Hc[m][(t + 3) >> 2][(t + 3) & 3]) : 0.0f;
      }
      bf8 r8;
#pragma unroll
      for (int d = 0; d < 8; ++d) {
        const int j = j0 + d;
        unsigned short rv = 0;
        if (j < 90) {  // cols 90..95 stay zero (fc1 K-slots 90..95 are zero)
          float acc = cbv;
#pragma unroll
          for (int k = 0; k < 7; ++k) {  // same FMA order as validated conv
            acc = fmaf(v0[d + k], cwr[k], acc);
            acc = fmaf(v1[d + k], cwr[7 + k], acc);
          }
          rv = f2bf(fmaxf(acc, 0.0f));
        }
        r8[d] = (short)rv;
      }
      ya[m][ks] = r8;
    }
  }

  // ---- fc1: K=96; each wb fragment (global w1b) feeds both m-tiles ----
#pragma unroll
  for (int nt = 0; nt < 8; ++nt) {
    bf8 wb[3];
#pragma unroll
    for (int ks = 0; ks < 3; ++ks)
      wb[ks] = *(const bf8*)&w1b[(16 * nt + l15) * 104 + 32 * ks + 8 * q];
    f32x4 a0 = {0.f, 0.f, 0.f, 0.f}, a1 = {0.f, 0.f, 0.f, 0.f};
#pragma unroll
    for (int ks = 0; ks < 3; ++ks) {
      a0 = __builtin_amdgcn_mfma_f32_16x16x32_bf16(ya[0][ks], wb[ks], a0, 0, 0, 0);
      a1 = __builtin_amdgcn_mfma_f32_16x16x32_bf16(ya[1][ks], wb[ks], a1, 0, 0, 0);
    }
    // epilogue 1: +b1, relu -> H[n][o1] bf16 (wave-private rows)
#pragma unroll
    for (int r = 0; r < 4; ++r) {
      const int o = 16 * nt + l15;
      Hs[(32 * w + 4 * q + r) * 136 + o]      = f2bf(fmaxf(a0[r] + b1v[nt], 0.0f));
      Hs[(32 * w + 16 + 4 * q + r) * 136 + o] = f2bf(fmaxf(a1[r] + b1v[nt], 0.0f));
    }
  }

  // ---- fc2: K=128, 16 output tiles; wb (global w2b) feeds both m-tiles ----
  bf8 ha[2][4];
#pragma unroll
  for (int m = 0; m < 2; ++m)
#pragma unroll
    for (int ks = 0; ks < 4; ++ks)
      ha[m][ks] = *(const bf8*)&Hs[(32 * w + 16 * m + l15) * 136 + 32 * ks + 8 * q];

#pragma unroll 4
  for (int nt = 0; nt < 16; ++nt) {
    bf8 wb[4];
#pragma unroll
    for (int ks = 0; ks < 4; ++ks)
      wb[ks] = *(const bf8*)&w2b[(16 * nt + l15) * 136 + 32 * ks + 8 * q];
    f32x4 a0 = {0.f, 0.f, 0.f, 0.f}, a1 = {0.f, 0.f, 0.f, 0.f};
#pragma unroll
    for (int ks = 0; ks < 4; ++ks) {
      a0 = __builtin_amdgcn_mfma_f32_16x16x32_bf16(ha[0][ks], wb[ks], a0, 0, 0, 0);
      a1 = __builtin_amdgcn_mfma_f32_16x16x32_bf16(ha[1][ks], wb[ks], a1, 0, 0, 0);
    }
#pragma unroll
    for (int r = 0; r < 4; ++r) {
      const int o = 16 * nt + l15;
      out[(g0 + 32 * w + 4 * q + r) * 256 + o]      = a0[r] + b2v[nt];
      out[(g0 + 32 * w + 16 + 4 * q + r) * 256 + o] = a1[r] + b2v[nt];
    }
  }
}

// ---------------------------------------------------------------------------
extern "C" void kernel_launch(void* const* d_in, const int* in_sizes, int n_in,
                              void* d_out, int out_size, void* d_ws, size_t ws_size,
                              hipStream_t stream) {
  const float* x  = (const float*)d_in[0];
  const float* cw = (const float*)d_in[1];
  const float* cb = (const float*)d_in[2];
  const float* w1 = (const float*)d_in[3];
  const float* b1 = (const float*)d_in[4];
  const float* w2 = (const float*)d_in[5];
  const float* b2 = (const float*)d_in[6];
  float* outp = (float*)d_out;

  // Weights FIRST so A's row-0 conv window under-read stays in-allocation.
  unsigned short* w1b = (unsigned short*)d_ws;      // 13312 u16 (128x104)
  unsigned short* w2b = w1b + 13312;                // 34816 u16 (256x136)
  unsigned short* Abf = w1b + 48128;                // 16*180*4096 u16 = 23.6 MB

  dwt2_kernel<<<559, 256, 0, stream>>>(x, Abf, w1, w2, w1b, w2b);
  mlp_direct_kernel<<<512, 256, 0, stream>>>(Abf, cw, cb, w1b, w2b, b1, b2, outp);
}